// Round 7
// baseline (233.252 us; speedup 1.0000x reference)
//
#include <hip/hip_runtime.h>

#define DD 16
#define HH 128
#define WW 128
#define DHW (DD * HH * WW)   // 262144
#define CIN 16
#define COUT 32
#define KK 27
#define NOFF 81
#define NKC 14               // K-chunks of 32 over (tap,ci); taps padded 27->28
#define NNT 6                // phase-1 n-tiles of 16 over 81->96

typedef _Float16 h2    __attribute__((ext_vector_type(2)));
typedef _Float16 f16x8 __attribute__((ext_vector_type(8)));
typedef float    f32x4 __attribute__((ext_vector_type(4)));
struct H16 { h2 v[8]; };     // 16 fp16 channels = 32 B

// ---- ws layout ----
// [0, 8MB)      xt    : fp16 [vox][16]
// [8MB,+84K)    wBf   : off_w in MFMA B-frag order [kc][n][lane][8]   (A)
// [next,+28K)   wW3   : weight in MFMA A-frag order [kc][mo][lane][8] (B)
// [aligned,+42.5MB) loff_g : fp16 [j=3t+c][DHW]  (A writes, B reads)
#define XT_BYTES    ((size_t)DHW * CIN * 2)            // 8 MiB
#define WBF_OFF     XT_BYTES
#define WBF_ELEMS   (NKC * NNT * 64 * 8)               // 43008 halves
#define WW3_OFF     (WBF_OFF + (size_t)WBF_ELEMS * 2)
#define WW3_ELEMS   (NKC * 2 * 64 * 8)                 // 14336 halves
#define WFUSED_NEED (WW3_OFF + (size_t)WW3_ELEMS * 2)
#define LOFF_OFF    ((WFUSED_NEED + 255) & ~(size_t)255)
#define LOFF_BYTES  ((size_t)NOFF * DHW * 2)           // 42.5 MB
#define WS_SPLIT    (LOFF_OFF + LOFF_BYTES)

__device__ __forceinline__ float fast_tanh(float s) {
    float e = __expf(fminf(2.f * s, 80.f));
    return (e - 1.f) * __builtin_amdgcn_rcpf(e + 1.f);
}

// x [ci][vox] fp32  ->  xt [vox][ci] fp16
__global__ __launch_bounds__(256) void transpose_x_h(const float* __restrict__ x,
                                                     H16* __restrict__ xt) {
    int vox = blockIdx.x * 256 + threadIdx.x;
    if (vox >= DHW) return;
    H16 o;
#pragma unroll
    for (int p = 0; p < 8; ++p) {
        o.v[p][0] = (_Float16)x[(size_t)(2 * p) * DHW + vox];
        o.v[p][1] = (_Float16)x[(size_t)(2 * p + 1) * DHW + vox];
    }
    xt[vox] = o;
}

// Pack off_w into phase-1 B fragments and weight into phase-3 A fragments.
__global__ __launch_bounds__(256) void pack_w(const float* __restrict__ off_w,
                                              const float* __restrict__ weight,
                                              _Float16* __restrict__ wBf,
                                              _Float16* __restrict__ wW3) {
    int idx = blockIdx.x * 256 + threadIdx.x;
    if (idx < WBF_ELEMS) {
        int i    = idx & 7;
        int lane = (idx >> 3) & 63;
        int fn   = idx >> 9;            // kc*NNT + n
        int n    = fn % NNT;
        int kc   = fn / NNT;
        int g    = lane >> 4;
        int t    = kc * 2 + (g >> 1);
        int ci   = (g & 1) * 8 + i;
        int j    = n * 16 + (lane & 15);
        float v = 0.f;
        if (t < KK && j < NOFF) v = off_w[(size_t)(j * CIN + ci) * KK + t];
        wBf[idx] = (_Float16)v;
    }
    if (idx < WW3_ELEMS) {
        int i    = idx & 7;
        int lane = (idx >> 3) & 63;
        int fm   = idx >> 9;            // kc*2 + mo
        int mo   = fm & 1;
        int kc   = fm >> 1;
        int g    = lane >> 4;
        int t    = kc * 2 + (g >> 1);
        int ci   = (g & 1) * 8 + i;
        int o    = mo * 16 + (lane & 15);
        float v = 0.f;
        if (t < KK) v = weight[(size_t)(o * CIN + ci) * KK + t];
        wW3[idx] = (_Float16)v;
    }
}

// ---------------------------------------------------------------------------
// Kernel A: offset conv (MFMA implicit GEMM) -> tanh/scale -> loff_g planes.
// ---------------------------------------------------------------------------
__global__ __launch_bounds__(128, 3) void deform_offsets(
    const f16x8* __restrict__ xt16,   // 2 per voxel (8 ch each)
    const f16x8* __restrict__ wBf,    // phase-1 B fragments
    const float* __restrict__ off_b,  // [81]
    _Float16* __restrict__ loff_g)    // [81][DHW]
{
    __shared__ _Float16 loff[128 * 84];

    const int lb = ((blockIdx.x & 7) << 8) | (blockIdx.x >> 3);  // XCD swizzle
    const int h = lb & (HH - 1);
    const int d = lb >> 7;
    const int lane = threadIdx.x & 63;
    const int wave = threadIdx.x >> 6;
    const int g = lane >> 4;
    const int col = lane & 15;

    f32x4 acc[4][NNT];
#pragma unroll
    for (int mi = 0; mi < 4; ++mi)
#pragma unroll
        for (int n = 0; n < NNT; ++n) acc[mi][n] = f32x4{0.f, 0.f, 0.f, 0.f};

#pragma unroll 1
    for (int kc = 0; kc < NKC; ++kc) {
        const int t  = kc * 2 + (g >> 1);
        const int tz = t / 9, ty = (t / 3) % 3, tx = t % 3;
        const int zz = d + tz - 1, yy = h + ty - 1;
        const bool okzy = (t < KK) && ((unsigned)zz < (unsigned)DD) &&
                          ((unsigned)yy < (unsigned)HH);
        const int zc = min(max(zz, 0), DD - 1);
        const int yc = min(max(yy, 0), HH - 1);
        const int rowbase = (zc * HH + yc) * WW;
        const int txm1 = tx - 1;
        const int half = g & 1;

        f16x8 bfr[NNT];
#pragma unroll
        for (int n = 0; n < NNT; ++n) bfr[n] = wBf[(kc * NNT + n) * 64 + lane];

#pragma unroll
        for (int mi = 0; mi < 4; ++mi) {
            const int xx = (wave * 4 + mi) * 16 + col + txm1;
            const bool ok = okzy && ((unsigned)xx < (unsigned)WW);
            const int xc = min(max(xx, 0), WW - 1);
            union { f16x8 v; uint4 u; } au;
            au.v = xt16[(size_t)(rowbase + xc) * 2 + half];
            if (!ok) au.u = make_uint4(0u, 0u, 0u, 0u);
#pragma unroll
            for (int n = 0; n < NNT; ++n)
                acc[mi][n] = __builtin_amdgcn_mfma_f32_16x16x32_f16(
                    au.v, bfr[n], acc[mi][n], 0, 0, 0);
        }
    }

    // +off_b, tanh, scale -> LDS (fragment layout -> row layout)
#pragma unroll
    for (int n = 0; n < NNT; ++n) {
        const int j = n * 16 + col;
        if (j < NOFF) {
            const float ob = off_b[j];
            const float sc = (j % 3 == 2) ? 2.f : 4.f;
#pragma unroll
            for (int mi = 0; mi < 4; ++mi) {
#pragma unroll
                for (int r = 0; r < 4; ++r) {
                    const int vl = (wave * 4 + mi) * 16 + g * 4 + r;
                    loff[vl * 84 + j] =
                        (_Float16)(fast_tanh(acc[mi][n][r] + ob) * sc);
                }
            }
        }
    }
    __syncthreads();

    // coalesced write-out: plane j, vox = rowBase + w
    const int w = threadIdx.x;
    const size_t base = (size_t)(d * HH + h) * WW + w;
#pragma unroll 3
    for (int j = 0; j < NOFF; ++j)
        loff_g[(size_t)j * DHW + base] = loff[w * 84 + j];
}

// ---------------------------------------------------------------------------
// Kernel B: trilinear sample in B-fragment layout + MFMA contraction.
// 256 thr = 4 waves, 32 voxels/wave (one (d,h) row per block) -> high occupancy.
// ---------------------------------------------------------------------------
__global__ __launch_bounds__(256, 6) void deform_sample(
    const f16x8* __restrict__ xt16,   // 2 per voxel (8 ch each)
    const f16x8* __restrict__ wW3,    // phase-3 A fragments
    const _Float16* __restrict__ loff_g, // [81][DHW]
    const float* __restrict__ bias,   // [32]
    float* __restrict__ out)          // [32][DHW]
{
    const int lb = ((blockIdx.x & 7) << 8) | (blockIdx.x >> 3);  // XCD swizzle
    const int h = lb & (HH - 1);
    const int d = lb >> 7;
    const int lane = threadIdx.x & 63;
    const int wave = threadIdx.x >> 6;   // 0..3
    const int g = lane >> 4;
    const int col = lane & 15;
    const int half = g & 1;
    const int rowBase = (d * HH + h) * WW;

    f32x4 acc3[2][2];
#pragma unroll
    for (int mo = 0; mo < 2; ++mo)
#pragma unroll
        for (int nv = 0; nv < 2; ++nv) acc3[mo][nv] = f32x4{0.f, 0.f, 0.f, 0.f};

#pragma unroll 1
    for (int kc = 0; kc < NKC; ++kc) {
        const int myTap = kc * 2 + (g >> 1);
        const bool tapValid = myTap < KK;
        const int tA = tapValid ? myTap : 0;

        const f16x8 aw0 = wW3[(kc * 2 + 0) * 64 + lane];
        const f16x8 aw1 = wW3[(kc * 2 + 1) * 64 + lane];

        const int rx = tA % 3 - 1, ry = (tA / 3) % 3 - 1, rz = tA / 9 - 1;
        const float gyb = (float)(h + 1 + ry);
        const float gzb = (float)(d + 1 + rz);
        const size_t lbase = (size_t)(tA * 3) * DHW + rowBase;

#pragma unroll
        for (int nv = 0; nv < 2; ++nv) {
            const int wv = wave * 32 + nv * 16 + col;   // local w of my column

            const float dxo = (float)loff_g[lbase + wv];
            const float dyo = (float)loff_g[lbase + DHW + wv];
            const float dzo = (float)loff_g[lbase + 2 * DHW + wv];

            const float gx = (float)(wv + 1 + rx) + dxo;
            const float gy = gyb + dyo;
            const float gz = gzb + dzo;
            const float fx0f = floorf(gx), fy0f = floorf(gy), fz0f = floorf(gz);
            const float fx = gx - fx0f, fy = gy - fy0f, fz = gz - fz0f;
            const int x0 = (int)fx0f - 1, y0 = (int)fy0f - 1, z0 = (int)fz0f - 1;
            const float ifx = 1.f - fx, ify = 1.f - fy, ifz = 1.f - fz;

            // R5-style: per-corner independent validity/clamp (max ILP)
            float cw[8];
            int cidx[8];
#pragma unroll
            for (int c = 0; c < 8; ++c) {
                const int cx = x0 + (c & 1);
                const int cy = y0 + ((c >> 1) & 1);
                const int cz = z0 + (c >> 2);
                const bool ok = tapValid &&
                                (unsigned)cx < (unsigned)WW &&
                                (unsigned)cy < (unsigned)HH &&
                                (unsigned)cz < (unsigned)DD;
                const float wt = ((c & 1) ? fx : ifx) *
                                 (((c >> 1) & 1) ? fy : ify) *
                                 ((c >> 2) ? fz : ifz);
                cw[c] = ok ? wt : 0.f;
                const int cxc = min(max(cx, 0), WW - 1);
                const int cyc = min(max(cy, 0), HH - 1);
                const int czc = min(max(cz, 0), DD - 1);
                cidx[c] = (czc * HH + cyc) * WW + cxc;
            }

            f16x8 cv[8];
#pragma unroll
            for (int c = 0; c < 8; ++c)
                cv[c] = xt16[(size_t)cidx[c] * 2 + half];

            union { f16x8 v; h2 s[4]; } sf;
#pragma unroll
            for (int p = 0; p < 4; ++p) { sf.s[p][0] = (_Float16)0.f; sf.s[p][1] = (_Float16)0.f; }
#pragma unroll
            for (int c = 0; c < 8; ++c) {
                const _Float16 wh = (_Float16)cw[c];
                h2 w2; w2[0] = wh; w2[1] = wh;
                const h2* cvp = (const h2*)&cv[c];
#pragma unroll
                for (int p = 0; p < 4; ++p)
                    sf.s[p] = sf.s[p] + w2 * cvp[p];
            }

            acc3[0][nv] = __builtin_amdgcn_mfma_f32_16x16x32_f16(
                aw0, sf.v, acc3[0][nv], 0, 0, 0);
            acc3[1][nv] = __builtin_amdgcn_mfma_f32_16x16x32_f16(
                aw1, sf.v, acc3[1][nv], 0, 0, 0);
        }
    }

    // store: D row = o-in-tile (4g+r), col = vox (16-lane contiguous)
#pragma unroll
    for (int mo = 0; mo < 2; ++mo) {
#pragma unroll
        for (int r = 0; r < 4; ++r) {
            const int o = mo * 16 + 4 * g + r;
            const float b = bias[o];
#pragma unroll
            for (int nv = 0; nv < 2; ++nv) {
                const int wv = wave * 32 + nv * 16 + col;
                out[(size_t)o * DHW + rowBase + wv] = acc3[mo][nv][r] + b;
            }
        }
    }
}

// ---------------------------------------------------------------------------
// Mid fallback: R5 fused kernel (ws fits xt+frags but not loff_g).
// ---------------------------------------------------------------------------
__global__ __launch_bounds__(128, 3) void deform_full(
    const f16x8* __restrict__ xt16,
    const f16x8* __restrict__ wBf,
    const f16x8* __restrict__ wW3,
    const float* __restrict__ off_b,
    const float* __restrict__ bias,
    float* __restrict__ out)
{
    __shared__ _Float16 loff[128 * 84];

    const int lb = ((blockIdx.x & 7) << 8) | (blockIdx.x >> 3);
    const int h = lb & (HH - 1);
    const int d = lb >> 7;
    const int lane = threadIdx.x & 63;
    const int wave = threadIdx.x >> 6;
    const int g = lane >> 4;
    const int col = lane & 15;

    f32x4 acc[4][NNT];
#pragma unroll
    for (int mi = 0; mi < 4; ++mi)
#pragma unroll
        for (int n = 0; n < NNT; ++n) acc[mi][n] = f32x4{0.f, 0.f, 0.f, 0.f};

#pragma unroll 1
    for (int kc = 0; kc < NKC; ++kc) {
        const int t  = kc * 2 + (g >> 1);
        const int tz = t / 9, ty = (t / 3) % 3, tx = t % 3;
        const int zz = d + tz - 1, yy = h + ty - 1;
        const bool okzy = (t < KK) && ((unsigned)zz < (unsigned)DD) &&
                          ((unsigned)yy < (unsigned)HH);
        const int zc = min(max(zz, 0), DD - 1);
        const int yc = min(max(yy, 0), HH - 1);
        const int rowbase = (zc * HH + yc) * WW;
        const int txm1 = tx - 1;
        const int half = g & 1;

        f16x8 bfr[NNT];
#pragma unroll
        for (int n = 0; n < NNT; ++n) bfr[n] = wBf[(kc * NNT + n) * 64 + lane];

#pragma unroll
        for (int mi = 0; mi < 4; ++mi) {
            const int xx = (wave * 4 + mi) * 16 + col + txm1;
            const bool ok = okzy && ((unsigned)xx < (unsigned)WW);
            const int xc = min(max(xx, 0), WW - 1);
            union { f16x8 v; uint4 u; } au;
            au.v = xt16[(size_t)(rowbase + xc) * 2 + half];
            if (!ok) au.u = make_uint4(0u, 0u, 0u, 0u);
#pragma unroll
            for (int n = 0; n < NNT; ++n)
                acc[mi][n] = __builtin_amdgcn_mfma_f32_16x16x32_f16(
                    au.v, bfr[n], acc[mi][n], 0, 0, 0);
        }
    }

#pragma unroll
    for (int n = 0; n < NNT; ++n) {
        const int j = n * 16 + col;
        if (j < NOFF) {
            const float ob = off_b[j];
            const float sc = (j % 3 == 2) ? 2.f : 4.f;
#pragma unroll
            for (int mi = 0; mi < 4; ++mi) {
#pragma unroll
                for (int r = 0; r < 4; ++r) {
                    const int vl = (wave * 4 + mi) * 16 + g * 4 + r;
                    loff[vl * 84 + j] =
                        (_Float16)(fast_tanh(acc[mi][n][r] + ob) * sc);
                }
            }
        }
    }
    __syncthreads();

    f32x4 acc3[2][4];
#pragma unroll
    for (int mo = 0; mo < 2; ++mo)
#pragma unroll
        for (int nv = 0; nv < 4; ++nv) acc3[mo][nv] = f32x4{0.f, 0.f, 0.f, 0.f};

    const int half = g & 1;

#pragma unroll 1
    for (int kc = 0; kc < NKC; ++kc) {
        const int myTap = kc * 2 + (g >> 1);
        const bool tapValid = myTap < KK;
        const int tA = tapValid ? myTap : 0;

        const f16x8 aw0 = wW3[(kc * 2 + 0) * 64 + lane];
        const f16x8 aw1 = wW3[(kc * 2 + 1) * 64 + lane];

        const int rx = tA % 3 - 1, ry = (tA / 3) % 3 - 1, rz = tA / 9 - 1;

#pragma unroll
        for (int nv = 0; nv < 4; ++nv) {
            const int wv = wave * 64 + nv * 16 + col;

            float dxo = 0.f, dyo = 0.f, dzo = 0.f;
            if (tapValid) {
                dxo = (float)loff[wv * 84 + tA * 3 + 0];
                dyo = (float)loff[wv * 84 + tA * 3 + 1];
                dzo = (float)loff[wv * 84 + tA * 3 + 2];
            }

            const float gx = (float)(wv + 1 + rx) + dxo;
            const float gy = (float)(h + 1 + ry) + dyo;
            const float gz = (float)(d + 1 + rz) + dzo;
            const float fx0f = floorf(gx), fy0f = floorf(gy), fz0f = floorf(gz);
            const float fx = gx - fx0f, fy = gy - fy0f, fz = gz - fz0f;
            const int x0 = (int)fx0f - 1, y0 = (int)fy0f - 1, z0 = (int)fz0f - 1;
            const float ifx = 1.f - fx, ify = 1.f - fy, ifz = 1.f - fz;

            float cw[8];
            int cidx[8];
#pragma unroll
            for (int c = 0; c < 8; ++c) {
                const int cx = x0 + (c & 1);
                const int cy = y0 + ((c >> 1) & 1);
                const int cz = z0 + (c >> 2);
                const bool ok = tapValid &&
                                (unsigned)cx < (unsigned)WW &&
                                (unsigned)cy < (unsigned)HH &&
                                (unsigned)cz < (unsigned)DD;
                const float wt = ((c & 1) ? fx : ifx) *
                                 (((c >> 1) & 1) ? fy : ify) *
                                 ((c >> 2) ? fz : ifz);
                cw[c] = ok ? wt : 0.f;
                const int cxc = min(max(cx, 0), WW - 1);
                const int cyc = min(max(cy, 0), HH - 1);
                const int czc = min(max(cz, 0), DD - 1);
                cidx[c] = (czc * HH + cyc) * WW + cxc;
            }

            f16x8 cv[8];
#pragma unroll
            for (int c = 0; c < 8; ++c)
                cv[c] = xt16[(size_t)cidx[c] * 2 + half];

            union { f16x8 v; h2 s[4]; } sf;
#pragma unroll
            for (int p = 0; p < 4; ++p) { sf.s[p][0] = (_Float16)0.f; sf.s[p][1] = (_Float16)0.f; }
#pragma unroll
            for (int c = 0; c < 8; ++c) {
                const _Float16 wh = (_Float16)cw[c];
                h2 w2; w2[0] = wh; w2[1] = wh;
                const h2* cvp = (const h2*)&cv[c];
#pragma unroll
                for (int p = 0; p < 4; ++p)
                    sf.s[p] = sf.s[p] + w2 * cvp[p];
            }

            acc3[0][nv] = __builtin_amdgcn_mfma_f32_16x16x32_f16(
                aw0, sf.v, acc3[0][nv], 0, 0, 0);
            acc3[1][nv] = __builtin_amdgcn_mfma_f32_16x16x32_f16(
                aw1, sf.v, acc3[1][nv], 0, 0, 0);
        }
    }

    const int rowBase = (d * HH + h) * WW;
#pragma unroll
    for (int mo = 0; mo < 2; ++mo) {
#pragma unroll
        for (int r = 0; r < 4; ++r) {
            const int o = mo * 16 + 4 * g + r;
            const float b = bias[o];
#pragma unroll
            for (int nv = 0; nv < 4; ++nv) {
                const int wv = wave * 64 + nv * 16 + col;
                out[(size_t)o * DHW + rowBase + wv] = acc3[mo][nv][r] + b;
            }
        }
    }
}

// ---------------------------------------------------------------------------
// Last-resort fallback (tiny ws): fully fp32, original x layout.
// ---------------------------------------------------------------------------
__global__ __launch_bounds__(128) void deform_fallback(
    const float* __restrict__ x,
    const float* __restrict__ weight,
    const float* __restrict__ bias,
    const float* __restrict__ off_w,
    const float* __restrict__ off_b,
    float* __restrict__ out)
{
    const int w = threadIdx.x;
    const int h = blockIdx.x & (HH - 1);
    const int d = blockIdx.x >> 7;

    float outacc[COUT];
#pragma unroll
    for (int o = 0; o < COUT; ++o) outacc[o] = 0.f;

    for (int k = 0; k < KK; ++k) {
        float a0 = 0.f, a1 = 0.f, a2 = 0.f;
        const float* w0 = off_w + (size_t)(k * 3 + 0) * (CIN * KK);
        const float* w1 = off_w + (size_t)(k * 3 + 1) * (CIN * KK);
        const float* w2 = off_w + (size_t)(k * 3 + 2) * (CIN * KK);
        for (int ci = 0; ci < CIN; ++ci) {
            const float* xc = x + (size_t)ci * DHW;
#pragma unroll
            for (int t = 0; t < KK; ++t) {
                const int tz = t / 9, ty = (t / 3) % 3, tx = t % 3;
                const int zz = d + tz - 1, yy = h + ty - 1, xx = w + tx - 1;
                const bool ok = (unsigned)zz < (unsigned)DD &&
                                (unsigned)yy < (unsigned)HH &&
                                (unsigned)xx < (unsigned)WW;
                const float v = ok ? xc[(zz * HH + yy) * WW + xx] : 0.f;
                a0 = fmaf(v, w0[ci * KK + t], a0);
                a1 = fmaf(v, w1[ci * KK + t], a1);
                a2 = fmaf(v, w2[ci * KK + t], a2);
            }
        }
        const float dxo = fast_tanh(a0 + off_b[k * 3 + 0]) * 4.f;
        const float dyo = fast_tanh(a1 + off_b[k * 3 + 1]) * 4.f;
        const float dzo = fast_tanh(a2 + off_b[k * 3 + 2]) * 2.f;

        const int rx = k % 3 - 1, ry = (k / 3) % 3 - 1, rz = k / 9 - 1;
        const float gx = (float)(w + 1 + rx) + dxo;
        const float gy = (float)(h + 1 + ry) + dyo;
        const float gz = (float)(d + 1 + rz) + dzo;
        const float fx0 = floorf(gx), fy0 = floorf(gy), fz0 = floorf(gz);
        const float fx = gx - fx0, fy = gy - fy0, fz = gz - fz0;
        const int x0 = (int)fx0 - 1, y0 = (int)fy0 - 1, z0 = (int)fz0 - 1;

        float samp[CIN];
#pragma unroll
        for (int ci = 0; ci < CIN; ++ci) samp[ci] = 0.f;
#pragma unroll
        for (int c = 0; c < 8; ++c) {
            const int cx = x0 + (c & 1);
            const int cy = y0 + ((c >> 1) & 1);
            const int cz = z0 + (c >> 2);
            const float wt = ((c & 1) ? fx : 1.f - fx) *
                             (((c >> 1) & 1) ? fy : 1.f - fy) *
                             ((c >> 2) ? fz : 1.f - fz);
            if ((unsigned)cx < (unsigned)WW && (unsigned)cy < (unsigned)HH &&
                (unsigned)cz < (unsigned)DD) {
                const float* p = x + ((cz * HH) + cy) * WW + cx;
#pragma unroll
                for (int ci = 0; ci < 16; ++ci)
                    samp[ci] = fmaf(wt, p[(size_t)ci * DHW], samp[ci]);
            }
        }
#pragma unroll
        for (int o = 0; o < COUT; ++o) {
            float s = 0.f;
#pragma unroll
            for (int ci = 0; ci < 16; ++ci)
                s = fmaf(weight[(o * CIN + ci) * KK + k], samp[ci], s);
            outacc[o] += s;
        }
    }
    const int vox = (d * HH + h) * WW + w;
#pragma unroll
    for (int o = 0; o < COUT; ++o)
        out[(size_t)o * DHW + vox] = outacc[o] + bias[o];
}

extern "C" void kernel_launch(void* const* d_in, const int* in_sizes, int n_in,
                              void* d_out, int out_size, void* d_ws, size_t ws_size,
                              hipStream_t stream) {
    const float* x      = (const float*)d_in[0];
    const float* weight = (const float*)d_in[1];
    const float* bias   = (const float*)d_in[2];
    const float* off_w  = (const float*)d_in[3];
    const float* off_b  = (const float*)d_in[4];
    float* out = (float*)d_out;

    if (ws_size >= WFUSED_NEED) {
        H16* xt = (H16*)d_ws;
        _Float16* wBf = (_Float16*)((char*)d_ws + WBF_OFF);
        _Float16* wW3 = (_Float16*)((char*)d_ws + WW3_OFF);
        pack_w<<<(WBF_ELEMS + 255) / 256, 256, 0, stream>>>(off_w, weight, wBf, wW3);
        transpose_x_h<<<(DHW + 255) / 256, 256, 0, stream>>>(x, xt);
        if (ws_size >= WS_SPLIT) {
            _Float16* loff_g = (_Float16*)((char*)d_ws + LOFF_OFF);
            deform_offsets<<<DD * HH, 128, 0, stream>>>(
                (const f16x8*)xt, (const f16x8*)wBf, off_b, loff_g);
            deform_sample<<<DD * HH, 256, 0, stream>>>(
                (const f16x8*)xt, (const f16x8*)wW3, loff_g, bias, out);
        } else {
            deform_full<<<DD * HH, 128, 0, stream>>>(
                (const f16x8*)xt, (const f16x8*)wBf, (const f16x8*)wW3,
                off_b, bias, out);
        }
    } else {
        deform_fallback<<<DD * HH, 128, 0, stream>>>(x, weight, bias, off_w, off_b, out);
    }
}

// Round 8
// 230.889 us; speedup vs baseline: 1.0102x; 1.0102x over previous
//
#include <hip/hip_runtime.h>

#define DD 16
#define HH 128
#define WW 128
#define DHW (DD * HH * WW)   // 262144
#define CIN 16
#define COUT 32
#define KK 27
#define NOFF 81
#define NKC 14               // K-chunks of 32 over (tap,ci); taps padded 27->28
#define NNT 6                // phase-1 n-tiles of 16 over 81->96

typedef _Float16 h2    __attribute__((ext_vector_type(2)));
typedef _Float16 f16x8 __attribute__((ext_vector_type(8)));
typedef float    f32x4 __attribute__((ext_vector_type(4)));
struct H16 { h2 v[8]; };     // 16 fp16 channels = 32 B

// ---- ws layout ----
// [0, 8MB)    xt  : fp16 [vox][16]
// [8MB,+84K)  wBf : off_w in MFMA B-frag order [kc][n][lane][8]   (phase 1)
// [next,+28K) wW3 : weight in MFMA A-frag order [kc][mo][lane][8] (phase 3)
#define XT_BYTES   ((size_t)DHW * CIN * 2)            // 8 MiB
#define WBF_OFF    XT_BYTES
#define WBF_ELEMS  (NKC * NNT * 64 * 8)               // 43008 halves
#define WW3_OFF    (WBF_OFF + (size_t)WBF_ELEMS * 2)
#define WW3_ELEMS  (NKC * 2 * 64 * 8)                 // 14336 halves
#define WS_NEED    (WW3_OFF + (size_t)WW3_ELEMS * 2)

__device__ __forceinline__ float fast_tanh(float s) {
    float e = __expf(fminf(2.f * s, 80.f));
    return (e - 1.f) * __builtin_amdgcn_rcpf(e + 1.f);
}

// x [ci][vox] fp32  ->  xt [vox][ci] fp16
__global__ __launch_bounds__(256) void transpose_x_h(const float* __restrict__ x,
                                                     H16* __restrict__ xt) {
    int vox = blockIdx.x * 256 + threadIdx.x;
    if (vox >= DHW) return;
    H16 o;
#pragma unroll
    for (int p = 0; p < 8; ++p) {
        o.v[p][0] = (_Float16)x[(size_t)(2 * p) * DHW + vox];
        o.v[p][1] = (_Float16)x[(size_t)(2 * p + 1) * DHW + vox];
    }
    xt[vox] = o;
}

// Pack off_w into phase-1 B fragments and weight into phase-3 A fragments.
__global__ __launch_bounds__(256) void pack_w(const float* __restrict__ off_w,
                                              const float* __restrict__ weight,
                                              _Float16* __restrict__ wBf,
                                              _Float16* __restrict__ wW3) {
    int idx = blockIdx.x * 256 + threadIdx.x;
    if (idx < WBF_ELEMS) {
        int i    = idx & 7;
        int lane = (idx >> 3) & 63;
        int fn   = idx >> 9;            // kc*NNT + n
        int n    = fn % NNT;
        int kc   = fn / NNT;
        int g    = lane >> 4;
        int t    = kc * 2 + (g >> 1);
        int ci   = (g & 1) * 8 + i;
        int j    = n * 16 + (lane & 15);
        float v = 0.f;
        if (t < KK && j < NOFF) v = off_w[(size_t)(j * CIN + ci) * KK + t];
        wBf[idx] = (_Float16)v;
    }
    if (idx < WW3_ELEMS) {
        int i    = idx & 7;
        int lane = (idx >> 3) & 63;
        int fm   = idx >> 9;            // kc*2 + mo
        int mo   = fm & 1;
        int kc   = fm >> 1;
        int g    = lane >> 4;
        int t    = kc * 2 + (g >> 1);
        int ci   = (g & 1) * 8 + i;
        int o    = mo * 16 + (lane & 15);
        float v = 0.f;
        if (t < KK) v = weight[(size_t)(o * CIN + ci) * KK + t];
        wW3[idx] = (_Float16)v;
    }
}

// ---------------------------------------------------------------------------
// Fused kernel, ONE WAVE per block (64 voxels = half a (d,h) row).
// The loff exchange is intra-wave -> no __syncthreads, 10.75KB LDS,
// 15 blocks/CU resident (vs 7 at 128thr/21.5KB). Inner loops = R5 verbatim.
// ---------------------------------------------------------------------------
__global__ __launch_bounds__(64, 4) void deform_full(
    const f16x8* __restrict__ xt16,   // 2 per voxel (8 ch each)
    const f16x8* __restrict__ wBf,    // phase-1 B fragments
    const f16x8* __restrict__ wW3,    // phase-3 A fragments
    const float* __restrict__ off_b,  // [81]
    const float* __restrict__ bias,   // [32]
    float* __restrict__ out)          // [32][DHW]
{
    // offsets for this wave's 64 voxels: [vox][tap*3+comp], stride 84 halves
    __shared__ _Float16 loff[64 * 84];

    // XCD swizzle: 4096 blocks, 8 XCDs, 512-block chunks (bijective)
    const int lb = ((blockIdx.x & 7) << 9) | (blockIdx.x >> 3);
    const int w0 = (lb & 1) * 64;          // which half-row
    const int row = lb >> 1;               // 0..2047
    const int h = row & (HH - 1);
    const int d = row >> 7;
    const int lane = threadIdx.x;          // 0..63
    const int g = lane >> 4;
    const int col = lane & 15;

    // ---- phase 1: offset conv as implicit GEMM (M=64 voxels) ----
    f32x4 acc[4][NNT];
#pragma unroll
    for (int mi = 0; mi < 4; ++mi)
#pragma unroll
        for (int n = 0; n < NNT; ++n) acc[mi][n] = f32x4{0.f, 0.f, 0.f, 0.f};

#pragma unroll 1
    for (int kc = 0; kc < NKC; ++kc) {
        const int t  = kc * 2 + (g >> 1);
        const int tz = t / 9, ty = (t / 3) % 3, tx = t % 3;
        const int zz = d + tz - 1, yy = h + ty - 1;
        const bool okzy = (t < KK) && ((unsigned)zz < (unsigned)DD) &&
                          ((unsigned)yy < (unsigned)HH);
        const int zc = min(max(zz, 0), DD - 1);
        const int yc = min(max(yy, 0), HH - 1);
        const int rowbase = (zc * HH + yc) * WW;
        const int txm1 = tx - 1;
        const int half = g & 1;

        f16x8 bfr[NNT];
#pragma unroll
        for (int n = 0; n < NNT; ++n) bfr[n] = wBf[(kc * NNT + n) * 64 + lane];

#pragma unroll
        for (int mi = 0; mi < 4; ++mi) {
            const int xx = w0 + mi * 16 + col + txm1;
            const bool ok = okzy && ((unsigned)xx < (unsigned)WW);
            const int xc = min(max(xx, 0), WW - 1);
            union { f16x8 v; uint4 u; } au;
            au.v = xt16[(size_t)(rowbase + xc) * 2 + half];
            if (!ok) au.u = make_uint4(0u, 0u, 0u, 0u);
#pragma unroll
            for (int n = 0; n < NNT; ++n)
                acc[mi][n] = __builtin_amdgcn_mfma_f32_16x16x32_f16(
                    au.v, bfr[n], acc[mi][n], 0, 0, 0);
        }
    }

    // ---- phase 1b: +off_b, tanh, scale -> LDS (intra-wave exchange) ----
#pragma unroll
    for (int n = 0; n < NNT; ++n) {
        const int j = n * 16 + col;
        if (j < NOFF) {
            const float ob = off_b[j];
            const float sc = (j % 3 == 2) ? 2.f : 4.f;
#pragma unroll
            for (int mi = 0; mi < 4; ++mi) {
#pragma unroll
                for (int r = 0; r < 4; ++r) {
                    const int vl = mi * 16 + g * 4 + r;   // wave-local voxel
                    loff[vl * 84 + j] =
                        (_Float16)(fast_tanh(acc[mi][n][r] + ob) * sc);
                }
            }
        }
    }
    __builtin_amdgcn_wave_barrier();   // order LDS writes before reads (1 wave)

    // ---- phase 2/3: sample in B-fragment layout + MFMA contraction ----
    f32x4 acc3[2][4];
#pragma unroll
    for (int mo = 0; mo < 2; ++mo)
#pragma unroll
        for (int nv = 0; nv < 4; ++nv) acc3[mo][nv] = f32x4{0.f, 0.f, 0.f, 0.f};

    const int half = g & 1;

#pragma unroll 1
    for (int kc = 0; kc < NKC; ++kc) {
        const int myTap = kc * 2 + (g >> 1);
        const bool tapValid = myTap < KK;
        const int tA = tapValid ? myTap : 0;

        const f16x8 aw0 = wW3[(kc * 2 + 0) * 64 + lane];
        const f16x8 aw1 = wW3[(kc * 2 + 1) * 64 + lane];

        const int rx = tA % 3 - 1, ry = (tA / 3) % 3 - 1, rz = tA / 9 - 1;

#pragma unroll
        for (int nv = 0; nv < 4; ++nv) {
            const int wv = nv * 16 + col;        // wave-local voxel
            const int wg = w0 + wv;              // global w coordinate

            float dxo = 0.f, dyo = 0.f, dzo = 0.f;
            if (tapValid) {
                dxo = (float)loff[wv * 84 + tA * 3 + 0];
                dyo = (float)loff[wv * 84 + tA * 3 + 1];
                dzo = (float)loff[wv * 84 + tA * 3 + 2];
            }

            const float gx = (float)(wg + 1 + rx) + dxo;
            const float gy = (float)(h + 1 + ry) + dyo;
            const float gz = (float)(d + 1 + rz) + dzo;
            const float fx0f = floorf(gx), fy0f = floorf(gy), fz0f = floorf(gz);
            const float fx = gx - fx0f, fy = gy - fy0f, fz = gz - fz0f;
            const int x0 = (int)fx0f - 1, y0 = (int)fy0f - 1, z0 = (int)fz0f - 1;
            const float ifx = 1.f - fx, ify = 1.f - fy, ifz = 1.f - fz;

            // per-corner independent validity/clamp (max ILP — R5 form)
            float cw[8];
            int cidx[8];
#pragma unroll
            for (int c = 0; c < 8; ++c) {
                const int cx = x0 + (c & 1);
                const int cy = y0 + ((c >> 1) & 1);
                const int cz = z0 + (c >> 2);
                const bool ok = tapValid &&
                                (unsigned)cx < (unsigned)WW &&
                                (unsigned)cy < (unsigned)HH &&
                                (unsigned)cz < (unsigned)DD;
                const float wt = ((c & 1) ? fx : ifx) *
                                 (((c >> 1) & 1) ? fy : ify) *
                                 ((c >> 2) ? fz : ifz);
                cw[c] = ok ? wt : 0.f;
                const int cxc = min(max(cx, 0), WW - 1);
                const int cyc = min(max(cy, 0), HH - 1);
                const int czc = min(max(cz, 0), DD - 1);
                cidx[c] = (czc * HH + cyc) * WW + cxc;
            }

            f16x8 cv[8];
#pragma unroll
            for (int c = 0; c < 8; ++c)
                cv[c] = xt16[(size_t)cidx[c] * 2 + half];

            union { f16x8 v; h2 s[4]; } sf;
#pragma unroll
            for (int p = 0; p < 4; ++p) { sf.s[p][0] = (_Float16)0.f; sf.s[p][1] = (_Float16)0.f; }
#pragma unroll
            for (int c = 0; c < 8; ++c) {
                const _Float16 wh = (_Float16)cw[c];
                h2 w2; w2[0] = wh; w2[1] = wh;
                const h2* cvp = (const h2*)&cv[c];
#pragma unroll
                for (int p = 0; p < 4; ++p)
                    sf.s[p] = sf.s[p] + w2 * cvp[p];
            }

            acc3[0][nv] = __builtin_amdgcn_mfma_f32_16x16x32_f16(
                aw0, sf.v, acc3[0][nv], 0, 0, 0);
            acc3[1][nv] = __builtin_amdgcn_mfma_f32_16x16x32_f16(
                aw1, sf.v, acc3[1][nv], 0, 0, 0);
        }
    }

    // ---- store: D row = o-in-tile (4g+r), col = vox (16-lane contiguous) ----
    const int rowBase = (d * HH + h) * WW + w0;
#pragma unroll
    for (int mo = 0; mo < 2; ++mo) {
#pragma unroll
        for (int r = 0; r < 4; ++r) {
            const int o = mo * 16 + 4 * g + r;
            const float b = bias[o];
#pragma unroll
            for (int nv = 0; nv < 4; ++nv) {
                const int wv = nv * 16 + col;
                out[(size_t)o * DHW + rowBase + wv] = acc3[mo][nv][r] + b;
            }
        }
    }
}

// ---------------------------------------------------------------------------
// Fallback (ws too small): fully fp32, original x layout.
// ---------------------------------------------------------------------------
__global__ __launch_bounds__(128) void deform_fallback(
    const float* __restrict__ x,
    const float* __restrict__ weight,
    const float* __restrict__ bias,
    const float* __restrict__ off_w,
    const float* __restrict__ off_b,
    float* __restrict__ out)
{
    const int w = threadIdx.x;
    const int h = blockIdx.x & (HH - 1);
    const int d = blockIdx.x >> 7;

    float outacc[COUT];
#pragma unroll
    for (int o = 0; o < COUT; ++o) outacc[o] = 0.f;

    for (int k = 0; k < KK; ++k) {
        float a0 = 0.f, a1 = 0.f, a2 = 0.f;
        const float* w0 = off_w + (size_t)(k * 3 + 0) * (CIN * KK);
        const float* w1 = off_w + (size_t)(k * 3 + 1) * (CIN * KK);
        const float* w2 = off_w + (size_t)(k * 3 + 2) * (CIN * KK);
        for (int ci = 0; ci < CIN; ++ci) {
            const float* xc = x + (size_t)ci * DHW;
#pragma unroll
            for (int t = 0; t < KK; ++t) {
                const int tz = t / 9, ty = (t / 3) % 3, tx = t % 3;
                const int zz = d + tz - 1, yy = h + ty - 1, xx = w + tx - 1;
                const bool ok = (unsigned)zz < (unsigned)DD &&
                                (unsigned)yy < (unsigned)HH &&
                                (unsigned)xx < (unsigned)WW;
                const float v = ok ? xc[(zz * HH + yy) * WW + xx] : 0.f;
                a0 = fmaf(v, w0[ci * KK + t], a0);
                a1 = fmaf(v, w1[ci * KK + t], a1);
                a2 = fmaf(v, w2[ci * KK + t], a2);
            }
        }
        const float dxo = fast_tanh(a0 + off_b[k * 3 + 0]) * 4.f;
        const float dyo = fast_tanh(a1 + off_b[k * 3 + 1]) * 4.f;
        const float dzo = fast_tanh(a2 + off_b[k * 3 + 2]) * 2.f;

        const int rx = k % 3 - 1, ry = (k / 3) % 3 - 1, rz = k / 9 - 1;
        const float gx = (float)(w + 1 + rx) + dxo;
        const float gy = (float)(h + 1 + ry) + dyo;
        const float gz = (float)(d + 1 + rz) + dzo;
        const float fx0 = floorf(gx), fy0 = floorf(gy), fz0 = floorf(gz);
        const float fx = gx - fx0, fy = gy - fy0, fz = gz - fz0;
        const int x0 = (int)fx0 - 1, y0 = (int)fy0 - 1, z0 = (int)fz0 - 1;

        float samp[CIN];
#pragma unroll
        for (int ci = 0; ci < CIN; ++ci) samp[ci] = 0.f;
#pragma unroll
        for (int c = 0; c < 8; ++c) {
            const int cx = x0 + (c & 1);
            const int cy = y0 + ((c >> 1) & 1);
            const int cz = z0 + (c >> 2);
            const float wt = ((c & 1) ? fx : 1.f - fx) *
                             (((c >> 1) & 1) ? fy : 1.f - fy) *
                             ((c >> 2) ? fz : 1.f - fz);
            if ((unsigned)cx < (unsigned)WW && (unsigned)cy < (unsigned)HH &&
                (unsigned)cz < (unsigned)DD) {
                const float* p = x + ((cz * HH) + cy) * WW + cx;
#pragma unroll
                for (int ci = 0; ci < 16; ++ci)
                    samp[ci] = fmaf(wt, p[(size_t)ci * DHW], samp[ci]);
            }
        }
#pragma unroll
        for (int o = 0; o < COUT; ++o) {
            float s = 0.f;
#pragma unroll
            for (int ci = 0; ci < 16; ++ci)
                s = fmaf(weight[(o * CIN + ci) * KK + k], samp[ci], s);
            outacc[o] += s;
        }
    }
    const int vox = (d * HH + h) * WW + w;
#pragma unroll
    for (int o = 0; o < COUT; ++o)
        out[(size_t)o * DHW + vox] = outacc[o] + bias[o];
}

extern "C" void kernel_launch(void* const* d_in, const int* in_sizes, int n_in,
                              void* d_out, int out_size, void* d_ws, size_t ws_size,
                              hipStream_t stream) {
    const float* x      = (const float*)d_in[0];
    const float* weight = (const float*)d_in[1];
    const float* bias   = (const float*)d_in[2];
    const float* off_w  = (const float*)d_in[3];
    const float* off_b  = (const float*)d_in[4];
    float* out = (float*)d_out;

    if (ws_size >= WS_NEED) {
        H16* xt = (H16*)d_ws;
        _Float16* wBf = (_Float16*)((char*)d_ws + WBF_OFF);
        _Float16* wW3 = (_Float16*)((char*)d_ws + WW3_OFF);
        pack_w<<<(WBF_ELEMS + 255) / 256, 256, 0, stream>>>(off_w, weight, wBf, wW3);
        transpose_x_h<<<(DHW + 255) / 256, 256, 0, stream>>>(x, xt);
        deform_full<<<DHW / 64, 64, 0, stream>>>((const f16x8*)xt, (const f16x8*)wBf,
                                                 (const f16x8*)wW3, off_b, bias, out);
    } else {
        deform_fallback<<<DD * HH, 128, 0, stream>>>(x, weight, bias, off_w, off_b, out);
    }
}

// Round 9
// 172.329 us; speedup vs baseline: 1.3535x; 1.3398x over previous
//
#include <hip/hip_runtime.h>

#define DD 16
#define HH 128
#define WW 128
#define DHW (DD * HH * WW)   // 262144
#define CIN 16
#define COUT 32
#define KK 27
#define NOFF 81
#define NKC 14               // K-chunks of 32 over (tap,ci); taps padded 27->28
#define NNT 6                // phase-1 n-tiles of 16 over 81->96

typedef _Float16 h2    __attribute__((ext_vector_type(2)));
typedef _Float16 f16x8 __attribute__((ext_vector_type(8)));
typedef float    f32x4 __attribute__((ext_vector_type(4)));
struct H16 { h2 v[8]; };     // 16 fp16 channels = 32 B

// ---- ws layout ----
// [0, 8MB)    xt  : fp16 [vox][16]
// [8MB,+84K)  wBf : off_w in MFMA B-frag order [kc][n][lane][8]   (phase 1)
// [next,+28K) wW3 : weight in MFMA A-frag order [kc][mo][lane][8] (phase 3)
#define XT_BYTES   ((size_t)DHW * CIN * 2)            // 8 MiB
#define WBF_OFF    XT_BYTES
#define WBF_ELEMS  (NKC * NNT * 64 * 8)               // 43008 halves
#define WW3_OFF    (WBF_OFF + (size_t)WBF_ELEMS * 2)
#define WW3_ELEMS  (NKC * 2 * 64 * 8)                 // 14336 halves
#define WS_NEED    (WW3_OFF + (size_t)WW3_ELEMS * 2)

__device__ __forceinline__ float fast_tanh(float s) {
    float e = __expf(fminf(2.f * s, 80.f));
    return (e - 1.f) * __builtin_amdgcn_rcpf(e + 1.f);
}

// x [ci][vox] fp32  ->  xt [vox][ci] fp16
__global__ __launch_bounds__(256) void transpose_x_h(const float* __restrict__ x,
                                                     H16* __restrict__ xt) {
    int vox = blockIdx.x * 256 + threadIdx.x;
    if (vox >= DHW) return;
    H16 o;
#pragma unroll
    for (int p = 0; p < 8; ++p) {
        o.v[p][0] = (_Float16)x[(size_t)(2 * p) * DHW + vox];
        o.v[p][1] = (_Float16)x[(size_t)(2 * p + 1) * DHW + vox];
    }
    xt[vox] = o;
}

// Pack off_w into phase-1 B fragments and weight into phase-3 A fragments.
__global__ __launch_bounds__(256) void pack_w(const float* __restrict__ off_w,
                                              const float* __restrict__ weight,
                                              _Float16* __restrict__ wBf,
                                              _Float16* __restrict__ wW3) {
    int idx = blockIdx.x * 256 + threadIdx.x;
    if (idx < WBF_ELEMS) {
        int i    = idx & 7;
        int lane = (idx >> 3) & 63;
        int fn   = idx >> 9;            // kc*NNT + n
        int n    = fn % NNT;
        int kc   = fn / NNT;
        int g    = lane >> 4;
        int t    = kc * 2 + (g >> 1);
        int ci   = (g & 1) * 8 + i;
        int j    = n * 16 + (lane & 15);
        float v = 0.f;
        if (t < KK && j < NOFF) v = off_w[(size_t)(j * CIN + ci) * KK + t];
        wBf[idx] = (_Float16)v;
    }
    if (idx < WW3_ELEMS) {
        int i    = idx & 7;
        int lane = (idx >> 3) & 63;
        int fm   = idx >> 9;            // kc*2 + mo
        int mo   = fm & 1;
        int kc   = fm >> 1;
        int g    = lane >> 4;
        int t    = kc * 2 + (g >> 1);
        int ci   = (g & 1) * 8 + i;
        int o    = mo * 16 + (lane & 15);
        float v = 0.f;
        if (t < KK) v = weight[(size_t)(o * CIN + ci) * KK + t];
        wW3[idx] = (_Float16)v;
    }
}

// ---------------------------------------------------------------------------
// Fused kernel (R5 structure): phase 1 = MFMA implicit-GEMM offset conv;
// phase 2/3 = per-lane trilinear sampling in B-fragment layout + MFMA
// contraction. Single change vs R5: kc loop unrolled 2x to double the
// schedulable gather window (two independent load batches in flight).
// ---------------------------------------------------------------------------
__global__ __launch_bounds__(128, 3) void deform_full(
    const f16x8* __restrict__ xt16,   // 2 per voxel (8 ch each)
    const f16x8* __restrict__ wBf,    // phase-1 B fragments
    const f16x8* __restrict__ wW3,    // phase-3 A fragments
    const float* __restrict__ off_b,  // [81]
    const float* __restrict__ bias,   // [32]
    float* __restrict__ out)          // [32][DHW]
{
    // offsets: [local w][tap*3+comp] fp16, row stride 84 halves (168B)
    __shared__ _Float16 loff[128 * 84];

    const int lb = ((blockIdx.x & 7) << 8) | (blockIdx.x >> 3);  // XCD swizzle
    const int h = lb & (HH - 1);
    const int d = lb >> 7;
    const int lane = threadIdx.x & 63;
    const int wave = threadIdx.x >> 6;
    const int g = lane >> 4;
    const int col = lane & 15;

    // ---- phase 1: offset conv as implicit GEMM ----
    f32x4 acc[4][NNT];
#pragma unroll
    for (int mi = 0; mi < 4; ++mi)
#pragma unroll
        for (int n = 0; n < NNT; ++n) acc[mi][n] = f32x4{0.f, 0.f, 0.f, 0.f};

#pragma unroll 1
    for (int kc = 0; kc < NKC; ++kc) {
        const int t  = kc * 2 + (g >> 1);
        const int tz = t / 9, ty = (t / 3) % 3, tx = t % 3;
        const int zz = d + tz - 1, yy = h + ty - 1;
        const bool okzy = (t < KK) && ((unsigned)zz < (unsigned)DD) &&
                          ((unsigned)yy < (unsigned)HH);
        const int zc = min(max(zz, 0), DD - 1);
        const int yc = min(max(yy, 0), HH - 1);
        const int rowbase = (zc * HH + yc) * WW;
        const int txm1 = tx - 1;
        const int half = g & 1;

        f16x8 bfr[NNT];
#pragma unroll
        for (int n = 0; n < NNT; ++n) bfr[n] = wBf[(kc * NNT + n) * 64 + lane];

#pragma unroll
        for (int mi = 0; mi < 4; ++mi) {
            const int xx = (wave * 4 + mi) * 16 + col + txm1;
            const bool ok = okzy && ((unsigned)xx < (unsigned)WW);
            const int xc = min(max(xx, 0), WW - 1);
            union { f16x8 v; uint4 u; } au;
            au.v = xt16[(size_t)(rowbase + xc) * 2 + half];
            if (!ok) au.u = make_uint4(0u, 0u, 0u, 0u);
#pragma unroll
            for (int n = 0; n < NNT; ++n)
                acc[mi][n] = __builtin_amdgcn_mfma_f32_16x16x32_f16(
                    au.v, bfr[n], acc[mi][n], 0, 0, 0);
        }
    }

    // ---- phase 1b: +off_b, tanh, scale -> LDS ----
#pragma unroll
    for (int n = 0; n < NNT; ++n) {
        const int j = n * 16 + col;
        if (j < NOFF) {
            const float ob = off_b[j];
            const float sc = (j % 3 == 2) ? 2.f : 4.f;
#pragma unroll
            for (int mi = 0; mi < 4; ++mi) {
#pragma unroll
                for (int r = 0; r < 4; ++r) {
                    const int vl = (wave * 4 + mi) * 16 + g * 4 + r;
                    loff[vl * 84 + j] =
                        (_Float16)(fast_tanh(acc[mi][n][r] + ob) * sc);
                }
            }
        }
    }
    __syncthreads();

    // ---- phase 2/3: sample in B-fragment layout + MFMA contraction ----
    f32x4 acc3[2][4];
#pragma unroll
    for (int mo = 0; mo < 2; ++mo)
#pragma unroll
        for (int nv = 0; nv < 4; ++nv) acc3[mo][nv] = f32x4{0.f, 0.f, 0.f, 0.f};

    const int half = g & 1;

#pragma unroll 2
    for (int kc = 0; kc < NKC; ++kc) {
        const int myTap = kc * 2 + (g >> 1);
        const bool tapValid = myTap < KK;
        const int tA = tapValid ? myTap : 0;

        const f16x8 aw0 = wW3[(kc * 2 + 0) * 64 + lane];
        const f16x8 aw1 = wW3[(kc * 2 + 1) * 64 + lane];

        const int rx = tA % 3 - 1, ry = (tA / 3) % 3 - 1, rz = tA / 9 - 1;

#pragma unroll
        for (int nv = 0; nv < 4; ++nv) {
            const int wv = wave * 64 + nv * 16 + col;   // local w of my column

            float dxo = 0.f, dyo = 0.f, dzo = 0.f;
            if (tapValid) {
                dxo = (float)loff[wv * 84 + tA * 3 + 0];
                dyo = (float)loff[wv * 84 + tA * 3 + 1];
                dzo = (float)loff[wv * 84 + tA * 3 + 2];
            }

            const float gx = (float)(wv + 1 + rx) + dxo;
            const float gy = (float)(h + 1 + ry) + dyo;
            const float gz = (float)(d + 1 + rz) + dzo;
            const float fx0f = floorf(gx), fy0f = floorf(gy), fz0f = floorf(gz);
            const float fx = gx - fx0f, fy = gy - fy0f, fz = gz - fz0f;
            const int x0 = (int)fx0f - 1, y0 = (int)fy0f - 1, z0 = (int)fz0f - 1;
            const float ifx = 1.f - fx, ify = 1.f - fy, ifz = 1.f - fz;

            // per-corner independent validity/clamp (max ILP — R5 form)
            float cw[8];
            int cidx[8];
#pragma unroll
            for (int c = 0; c < 8; ++c) {
                const int cx = x0 + (c & 1);
                const int cy = y0 + ((c >> 1) & 1);
                const int cz = z0 + (c >> 2);
                const bool ok = tapValid &&
                                (unsigned)cx < (unsigned)WW &&
                                (unsigned)cy < (unsigned)HH &&
                                (unsigned)cz < (unsigned)DD;
                const float wt = ((c & 1) ? fx : ifx) *
                                 (((c >> 1) & 1) ? fy : ify) *
                                 ((c >> 2) ? fz : ifz);
                cw[c] = ok ? wt : 0.f;
                const int cxc = min(max(cx, 0), WW - 1);
                const int cyc = min(max(cy, 0), HH - 1);
                const int czc = min(max(cz, 0), DD - 1);
                cidx[c] = (czc * HH + cyc) * WW + cxc;
            }

            f16x8 cv[8];
#pragma unroll
            for (int c = 0; c < 8; ++c)
                cv[c] = xt16[(size_t)cidx[c] * 2 + half];

            union { f16x8 v; h2 s[4]; } sf;
#pragma unroll
            for (int p = 0; p < 4; ++p) { sf.s[p][0] = (_Float16)0.f; sf.s[p][1] = (_Float16)0.f; }
#pragma unroll
            for (int c = 0; c < 8; ++c) {
                const _Float16 wh = (_Float16)cw[c];
                h2 w2; w2[0] = wh; w2[1] = wh;
                const h2* cvp = (const h2*)&cv[c];
#pragma unroll
                for (int p = 0; p < 4; ++p)
                    sf.s[p] = sf.s[p] + w2 * cvp[p];
            }

            acc3[0][nv] = __builtin_amdgcn_mfma_f32_16x16x32_f16(
                aw0, sf.v, acc3[0][nv], 0, 0, 0);
            acc3[1][nv] = __builtin_amdgcn_mfma_f32_16x16x32_f16(
                aw1, sf.v, acc3[1][nv], 0, 0, 0);
        }
    }

    // ---- store: D row = o-in-tile (4g+r), col = vox (16-lane contiguous) ----
    const int rowBase = (d * HH + h) * WW;
#pragma unroll
    for (int mo = 0; mo < 2; ++mo) {
#pragma unroll
        for (int r = 0; r < 4; ++r) {
            const int o = mo * 16 + 4 * g + r;
            const float b = bias[o];
#pragma unroll
            for (int nv = 0; nv < 4; ++nv) {
                const int wv = wave * 64 + nv * 16 + col;
                out[(size_t)o * DHW + rowBase + wv] = acc3[mo][nv][r] + b;
            }
        }
    }
}

// ---------------------------------------------------------------------------
// Fallback (ws too small): fully fp32, original x layout.
// ---------------------------------------------------------------------------
__global__ __launch_bounds__(128) void deform_fallback(
    const float* __restrict__ x,
    const float* __restrict__ weight,
    const float* __restrict__ bias,
    const float* __restrict__ off_w,
    const float* __restrict__ off_b,
    float* __restrict__ out)
{
    const int w = threadIdx.x;
    const int h = blockIdx.x & (HH - 1);
    const int d = blockIdx.x >> 7;

    float outacc[COUT];
#pragma unroll
    for (int o = 0; o < COUT; ++o) outacc[o] = 0.f;

    for (int k = 0; k < KK; ++k) {
        float a0 = 0.f, a1 = 0.f, a2 = 0.f;
        const float* w0 = off_w + (size_t)(k * 3 + 0) * (CIN * KK);
        const float* w1 = off_w + (size_t)(k * 3 + 1) * (CIN * KK);
        const float* w2 = off_w + (size_t)(k * 3 + 2) * (CIN * KK);
        for (int ci = 0; ci < CIN; ++ci) {
            const float* xc = x + (size_t)ci * DHW;
#pragma unroll
            for (int t = 0; t < KK; ++t) {
                const int tz = t / 9, ty = (t / 3) % 3, tx = t % 3;
                const int zz = d + tz - 1, yy = h + ty - 1, xx = w + tx - 1;
                const bool ok = (unsigned)zz < (unsigned)DD &&
                                (unsigned)yy < (unsigned)HH &&
                                (unsigned)xx < (unsigned)WW;
                const float v = ok ? xc[(zz * HH + yy) * WW + xx] : 0.f;
                a0 = fmaf(v, w0[ci * KK + t], a0);
                a1 = fmaf(v, w1[ci * KK + t], a1);
                a2 = fmaf(v, w2[ci * KK + t], a2);
            }
        }
        const float dxo = fast_tanh(a0 + off_b[k * 3 + 0]) * 4.f;
        const float dyo = fast_tanh(a1 + off_b[k * 3 + 1]) * 4.f;
        const float dzo = fast_tanh(a2 + off_b[k * 3 + 2]) * 2.f;

        const int rx = k % 3 - 1, ry = (k / 3) % 3 - 1, rz = k / 9 - 1;
        const float gx = (float)(w + 1 + rx) + dxo;
        const float gy = (float)(h + 1 + ry) + dyo;
        const float gz = (float)(d + 1 + rz) + dzo;
        const float fx0 = floorf(gx), fy0 = floorf(gy), fz0 = floorf(gz);
        const float fx = gx - fx0, fy = gy - fy0, fz = gz - fz0;
        const int x0 = (int)fx0 - 1, y0 = (int)fy0 - 1, z0 = (int)fz0 - 1;

        float samp[CIN];
#pragma unroll
        for (int ci = 0; ci < CIN; ++ci) samp[ci] = 0.f;
#pragma unroll
        for (int c = 0; c < 8; ++c) {
            const int cx = x0 + (c & 1);
            const int cy = y0 + ((c >> 1) & 1);
            const int cz = z0 + (c >> 2);
            const float wt = ((c & 1) ? fx : 1.f - fx) *
                             (((c >> 1) & 1) ? fy : 1.f - fy) *
                             ((c >> 2) ? fz : 1.f - fz);
            if ((unsigned)cx < (unsigned)WW && (unsigned)cy < (unsigned)HH &&
                (unsigned)cz < (unsigned)DD) {
                const float* p = x + ((cz * HH) + cy) * WW + cx;
#pragma unroll
                for (int ci = 0; ci < 16; ++ci)
                    samp[ci] = fmaf(wt, p[(size_t)ci * DHW], samp[ci]);
            }
        }
#pragma unroll
        for (int o = 0; o < COUT; ++o) {
            float s = 0.f;
#pragma unroll
            for (int ci = 0; ci < 16; ++ci)
                s = fmaf(weight[(o * CIN + ci) * KK + k], samp[ci], s);
            outacc[o] += s;
        }
    }
    const int vox = (d * HH + h) * WW + w;
#pragma unroll
    for (int o = 0; o < COUT; ++o)
        out[(size_t)o * DHW + vox] = outacc[o] + bias[o];
}

extern "C" void kernel_launch(void* const* d_in, const int* in_sizes, int n_in,
                              void* d_out, int out_size, void* d_ws, size_t ws_size,
                              hipStream_t stream) {
    const float* x      = (const float*)d_in[0];
    const float* weight = (const float*)d_in[1];
    const float* bias   = (const float*)d_in[2];
    const float* off_w  = (const float*)d_in[3];
    const float* off_b  = (const float*)d_in[4];
    float* out = (float*)d_out;

    if (ws_size >= WS_NEED) {
        H16* xt = (H16*)d_ws;
        _Float16* wBf = (_Float16*)((char*)d_ws + WBF_OFF);
        _Float16* wW3 = (_Float16*)((char*)d_ws + WW3_OFF);
        pack_w<<<(WBF_ELEMS + 255) / 256, 256, 0, stream>>>(off_w, weight, wBf, wW3);
        transpose_x_h<<<(DHW + 255) / 256, 256, 0, stream>>>(x, xt);
        deform_full<<<DD * HH, 128, 0, stream>>>((const f16x8*)xt, (const f16x8*)wBf,
                                                 (const f16x8*)wW3, off_b, bias, out);
    } else {
        deform_fallback<<<DD * HH, 128, 0, stream>>>(x, weight, bias, off_w, off_b, out);
    }
}